// Round 9
// baseline (84.655 us; speedup 1.0000x reference)
//
#include <hip/hip_runtime.h>

// out[b,c,l] = sum_r x[b,r,l] * weight[idx[b,l], r, c] + bias[idx[b,l], c]
//   x:       (4, 256, 32, 32) fp32   flat (b*256 + r)*1024 + l
//   indexes: (4096,) int             j in [0,8)
//   weight:  (8, 256, 256) fp32     (j*256 + r)*256 + c
//   bias:    (8, 256) fp32
//   out:     (4, 256, 32, 32) fp32  (b*256 + c)*1024 + l
//
// R9: two kernels.
//  1. convert_kernel: x -> xbf[b][l][k] bf16, weight -> wbf[j][c][k] bf16
//     (LDS 64x64 tile transposes, coalesced both sides). One launch, 384 blks.
//  2. gemm kernel: dense redundant-j MFMA as in R8, but fragments load
//     DIRECTLY from the k-contiguous bf16 arrays as 16 B dwordx4 (no LDS,
//     no barriers, no in-loop f2bf). Register double-buffered fragments.
// Fragment layouts verified on HW in R8 (16x16x32 bf16):
//   A[m=lane&15][k=quad*8+i], B[k=quad*8+i][n=lane&15], D[m=quad*4+r][n=lane&15]

#define C_DIM 256
#define KD    256
#define N_J   8

typedef __attribute__((ext_vector_type(8))) short bf16x8;
typedef __attribute__((ext_vector_type(4))) float f32x4;

__device__ __attribute__((aligned(16))) short g_xbf[4096 * KD];        // [b*1024+l][k]
__device__ __attribute__((aligned(16))) short g_wbf[N_J * C_DIM * KD]; // [j][c][k]

__device__ inline short f2bf(float f) {
    union { float f; unsigned u; } v; v.f = f;
    return (short)((v.u + 0x7FFFu + ((v.u >> 16) & 1u)) >> 16);  // RNE
}

// ---------------- Kernel 1: convert + transpose ----------------
// blocks 0..255: x tiles   (b = blk>>6, l-tile = (blk>>2)&15, k-tile = blk&3)
// blocks 256..383: w tiles (j = (blk-256)>>4, c-tile = ((blk-256)>>2)&3, k-tile = blk&3)
__global__ __launch_bounds__(256) void convert_kernel(const float* __restrict__ x,
                                                      const float* __restrict__ w)
{
    __shared__ float T[64][65];
    const int t    = threadIdx.x;
    const int lane = t & 63;
    const int grp  = t >> 6;
    const int blk  = blockIdx.x;

    if (blk < 256) {
        const int b  = blk >> 6;
        const int l0 = ((blk >> 2) & 15) * 64;
        const int k0 = (blk & 3) * 64;
        #pragma unroll
        for (int i = 0; i < 16; ++i) {
            const int kl = i * 4 + grp;
            T[kl][lane] = x[(b << 18) + ((k0 + kl) << 10) + l0 + lane]; // coalesced over l
        }
        __syncthreads();
        #pragma unroll
        for (int i = 0; i < 16; ++i) {
            const int ll = i * 4 + grp;
            g_xbf[((b << 10) + l0 + ll) * KD + k0 + lane] = f2bf(T[lane][ll]); // coalesced over k
        }
    } else {
        const int blk2 = blk - 256;
        const int j  = blk2 >> 4;
        const int c0 = ((blk2 >> 2) & 3) * 64;
        const int k0 = (blk2 & 3) * 64;
        #pragma unroll
        for (int i = 0; i < 16; ++i) {
            const int kl = i * 4 + grp;
            T[kl][lane] = w[(j * KD + k0 + kl) * C_DIM + c0 + lane];    // coalesced over c
        }
        __syncthreads();
        #pragma unroll
        for (int i = 0; i < 16; ++i) {
            const int cl = i * 4 + grp;
            g_wbf[(j * C_DIM + c0 + cl) * KD + k0 + lane] = f2bf(T[lane][cl]); // coalesced over k
        }
    }
}

// ---------------- Kernel 2: dense redundant-j MFMA GEMM ----------------
// grid (2 c-tiles, 32 l-tiles, 8 j), block 256 (4 waves, each 64c x 64l).
__global__ __launch_bounds__(256) void gemm_kernel(const int*   __restrict__ idx,
                                                   const float* __restrict__ bias,
                                                   float*       __restrict__ out)
{
    const int t    = threadIdx.x;
    const int lane = t & 63;
    const int wav  = t >> 6;
    const int quad = lane >> 4;
    const int li   = lane & 15;

    const int j   = blockIdx.z;
    const int c0  = blockIdx.x * 128 + (wav & 1) * 64;
    const int lg0 = blockIdx.y * 128 + (wav >> 1) * 64;
    const int b   = lg0 >> 10;

    // Fragment base pointers (16 B aligned: offsets are multiples of 8 shorts)
    const short* __restrict__ pa[4];
    const short* __restrict__ pb[4];
    #pragma unroll
    for (int mt = 0; mt < 4; ++mt)
        pa[mt] = g_wbf + ((j << 16) | ((c0 + mt * 16 + li) << 8)) + quad * 8;
    #pragma unroll
    for (int nt = 0; nt < 4; ++nt)
        pb[nt] = g_xbf + ((lg0 + nt * 16 + li) << 8) + quad * 8;

    f32x4 acc[4][4];
    #pragma unroll
    for (int mt = 0; mt < 4; ++mt)
        #pragma unroll
        for (int nt = 0; nt < 4; ++nt)
            acc[mt][nt] = (f32x4){0.f, 0.f, 0.f, 0.f};

    bf16x8 af[2][4], bfr[2][4];
    #pragma unroll
    for (int q = 0; q < 4; ++q) {
        af[0][q]  = *(const bf16x8*)(pa[q]);
        bfr[0][q] = *(const bf16x8*)(pb[q]);
    }

    #pragma unroll
    for (int kc = 0; kc < 8; ++kc) {
        const int p = kc & 1;
        if (kc < 7) {
            const int kofs = (kc + 1) * 32;
            #pragma unroll
            for (int q = 0; q < 4; ++q) {
                af[p ^ 1][q]  = *(const bf16x8*)(pa[q] + kofs);
                bfr[p ^ 1][q] = *(const bf16x8*)(pb[q] + kofs);
            }
        }
        #pragma unroll
        for (int mt = 0; mt < 4; ++mt)
            #pragma unroll
            for (int nt = 0; nt < 4; ++nt)
                acc[mt][nt] = __builtin_amdgcn_mfma_f32_16x16x32_bf16(
                    af[p][mt], bfr[p][nt], acc[mt][nt], 0, 0, 0);
    }

    // Epilogue: keep only elements whose token selects this j; add bias.
    #pragma unroll
    for (int mt = 0; mt < 4; ++mt) {
        const int cb = c0 + mt * 16 + quad * 4;
        const float4 bb = *(const float4*)(bias + j * C_DIM + cb);
        #pragma unroll
        for (int nt = 0; nt < 4; ++nt) {
            const int lg = lg0 + nt * 16 + li;
            if (idx[lg] != j) continue;
            float* __restrict__ op = out + (b << 18) + (cb << 10) + (lg & 1023);
            op[0 << 10] = acc[mt][nt][0] + bb.x;
            op[1 << 10] = acc[mt][nt][1] + bb.y;
            op[2 << 10] = acc[mt][nt][2] + bb.z;
            op[3 << 10] = acc[mt][nt][3] + bb.w;
        }
    }
}

extern "C" void kernel_launch(void* const* d_in, const int* in_sizes, int n_in,
                              void* d_out, int out_size, void* d_ws, size_t ws_size,
                              hipStream_t stream)
{
    const float* x      = (const float*)d_in[0];
    const int*   idx    = (const int*)  d_in[1];
    const float* weight = (const float*)d_in[2];
    const float* bias   = (const float*)d_in[3];
    float*       out    = (float*)      d_out;

    convert_kernel<<<384, 256, 0, stream>>>(x, weight);
    gemm_kernel<<<dim3(2, 32, 8), 256, 0, stream>>>(idx, bias, out);
}

// Round 10
// 76.307 us; speedup vs baseline: 1.1094x; 1.1094x over previous
//
#include <hip/hip_runtime.h>

// out[b,c,l] = sum_r x[b,r,l] * weight[idx[b,l], r, c] + bias[idx[b,l], c]
//   x:       (4, 256, 32, 32) fp32   flat (b*256 + r)*1024 + l
//   indexes: (4096,) int             j in [0,8)
//   weight:  (8, 256, 256) fp32     (j*256 + r)*256 + c
//   bias:    (8, 256) fp32
//   out:     (4, 256, 32, 32) fp32  (b*256 + c)*1024 + l
//
// R10: single kernel (R8 structure — best so far at 76.3 us) with the
// in-loop bf16 conversion cost cut ~3x (round-half-up instead of full RNE),
// explicit fp32 prefetch registers (loads for chunk k+1 in flight under
// cvt+MFMA of chunk k), and a hoisted epilogue (idx read once per nt).
// Dense redundant-j MFMA: all 8 W_j^T @ X computed, masked write.
//
// Fragment layouts verified on HW in R8 (16x16x32 bf16):
//   A[m=lane&15][k=quad*8+i], B[k=quad*8+i][n=lane&15], D[m=quad*4+r][n=lane&15]

#define C_DIM 256
#define KD    256

typedef __attribute__((ext_vector_type(8))) short bf16x8;
typedef __attribute__((ext_vector_type(4))) float f32x4;

// round-half-up bf16: 0.5-ulp max error (same bound as RNE, ties differ).
__device__ inline short f2b(float f) {
    union { float f; unsigned u; } v; v.f = f;
    return (short)((v.u + 0x8000u) >> 16);
}

__global__ __launch_bounds__(256) void fused_mfma_kernel(
    const float* __restrict__ x,
    const int*   __restrict__ idx,
    const float* __restrict__ weight,
    const float* __restrict__ bias,
    float*       __restrict__ out)
{
    const int t    = threadIdx.x;
    const int lane = t & 63;
    const int wav  = t >> 6;
    const int quad = lane >> 4;
    const int li   = lane & 15;

    const int j   = blockIdx.z;
    // wave tile: 64 c x 64 l inside a 128 x 128 block tile (waves 2x2)
    const int c0  = blockIdx.x * 128 + (wav & 1) * 64;
    const int lg0 = blockIdx.y * 128 + (wav >> 1) * 64;
    const int b   = lg0 >> 10;
    const int l0  = lg0 & 1023;

    // A source: W_j[k][c]; lane -> (c = c0+mt*16+li, k = quad*8+i)
    const float* __restrict__ wp =
        weight + j * (KD * C_DIM) + (quad * 8) * C_DIM + c0 + li;
    // B source: x[b][k][l]; lane -> (k = quad*8+i, l = l0+nt*16+li)
    const float* __restrict__ xp =
        x + (b << 18) + ((quad * 8) << 10) + l0 + li;

    f32x4 acc[4][4];
    #pragma unroll
    for (int mt = 0; mt < 4; ++mt)
        #pragma unroll
        for (int nt = 0; nt < 4; ++nt)
            acc[mt][nt] = (f32x4){0.f, 0.f, 0.f, 0.f};

    float raA[4][8], raB[4][8];     // fp32 prefetch buffers (chunk kc)
    // ---- prologue: load chunk 0 ----
    #pragma unroll
    for (int mt = 0; mt < 4; ++mt)
        #pragma unroll
        for (int i = 0; i < 8; ++i)
            raA[mt][i] = wp[i * C_DIM + mt * 16];
    #pragma unroll
    for (int nt = 0; nt < 4; ++nt)
        #pragma unroll
        for (int i = 0; i < 8; ++i)
            raB[nt][i] = xp[(i << 10) + nt * 16];

    #pragma unroll
    for (int kc = 0; kc < 8; ++kc) {
        // 1. convert prefetched fp32 -> bf16 fragments (frees raA/raB)
        bf16x8 af[4], bfr[4];
        #pragma unroll
        for (int mt = 0; mt < 4; ++mt)
            #pragma unroll
            for (int i = 0; i < 8; ++i) af[mt][i] = f2b(raA[mt][i]);
        #pragma unroll
        for (int nt = 0; nt < 4; ++nt)
            #pragma unroll
            for (int i = 0; i < 8; ++i) bfr[nt][i] = f2b(raB[nt][i]);

        // 2. issue next chunk's loads (in flight during MFMA below)
        if (kc < 7) {
            const int ko = (kc + 1) * 32;
            #pragma unroll
            for (int mt = 0; mt < 4; ++mt)
                #pragma unroll
                for (int i = 0; i < 8; ++i)
                    raA[mt][i] = wp[(ko + i) * C_DIM + mt * 16];
            #pragma unroll
            for (int nt = 0; nt < 4; ++nt)
                #pragma unroll
                for (int i = 0; i < 8; ++i)
                    raB[nt][i] = xp[((ko + i) << 10) + nt * 16];
        }

        // 3. 16 MFMAs on the matrix pipe
        #pragma unroll
        for (int mt = 0; mt < 4; ++mt)
            #pragma unroll
            for (int nt = 0; nt < 4; ++nt)
                acc[mt][nt] = __builtin_amdgcn_mfma_f32_16x16x32_bf16(
                    af[mt], bfr[nt], acc[mt][nt], 0, 0, 0);
    }

    // ---- epilogue: masked scatter, idx/bias hoisted ----
    bool keep[4];
    int  lgv[4];
    #pragma unroll
    for (int nt = 0; nt < 4; ++nt) {
        lgv[nt]  = lg0 + nt * 16 + li;
        keep[nt] = (idx[lgv[nt]] == j);
    }
    #pragma unroll
    for (int mt = 0; mt < 4; ++mt) {
        const int cb = c0 + mt * 16 + quad * 4;
        const float4 bb = *(const float4*)(bias + j * C_DIM + cb);
        #pragma unroll
        for (int nt = 0; nt < 4; ++nt) {
            if (!keep[nt]) continue;
            float* __restrict__ op = out + (b << 18) + (cb << 10) + (lgv[nt] & 1023);
            op[0 << 10] = acc[mt][nt][0] + bb.x;
            op[1 << 10] = acc[mt][nt][1] + bb.y;
            op[2 << 10] = acc[mt][nt][2] + bb.z;
            op[3 << 10] = acc[mt][nt][3] + bb.w;
        }
    }
}

extern "C" void kernel_launch(void* const* d_in, const int* in_sizes, int n_in,
                              void* d_out, int out_size, void* d_ws, size_t ws_size,
                              hipStream_t stream)
{
    const float* x      = (const float*)d_in[0];
    const int*   idx    = (const int*)  d_in[1];
    const float* weight = (const float*)d_in[2];
    const float* bias   = (const float*)d_in[3];
    float*       out    = (float*)      d_out;

    // grid: (2 c-tiles, 32 l-tiles, 8 j) = 512 blocks = 2 blocks/CU; j is
    // slowest (id diff 64 == 0 mod 8) so the 8 j-blocks of a (c,l) tile
    // share an XCD -> L2 merges their partial output lines.
    fused_mfma_kernel<<<dim3(2, 32, 8), 256, 0, stream>>>(x, idx, weight, bias, out);
}

// Round 11
// 74.079 us; speedup vs baseline: 1.1428x; 1.0301x over previous
//
#include <hip/hip_runtime.h>

// out[b,c,l] = sum_r x[b,r,l] * weight[idx[b,l], r, c] + bias[idx[b,l], c]
//   x:       (4, 256, 32, 32) fp32   flat (b*256 + r)*1024 + l
//   indexes: (4096,) int             j in [0,8)
//   weight:  (8, 256, 256) fp32     (j*256 + r)*256 + c
//   bias:    (8, 256) fp32
//   out:     (4, 256, 32, 32) fp32  (b*256 + c)*1024 + l
//
// R11: dense redundant-j MFMA (R8 math) with K-phased LDS staging.
// Key layout: LDS holds bf16 K-PAIRS packed in dwords, [k2][c] with row
// stride 132 dwords. Staging: coalesced float4 row-pair global loads ->
// pack 2 bf16 -> b128 LDS writes (conflict-free). Fragments: 4x
// ds_read_b32 per fragment (conflict-free: stride-132 rows spread quads
// across banks), dwords land in exact MFMA register order
// (VGPR d = bf16(k_even)|bf16(k_odd)<<16, k = quad*8+2d). Cuts per-wave
// VMEM from 512 scalar loads to 64 float4 loads.
//
// Fragment layouts verified on HW in R8 (16x16x32 bf16):
//   A[m=lane&15][k=quad*8+i], B[k=quad*8+i][n=lane&15], D[m=quad*4+r][n=lane&15]

#define C_DIM 256
#define KD    256
#define CB    128      // c per block
#define LB    128      // l per block
#define LDP   132      // LDS row stride (dwords) for k2-rows: (row*132+c)%32 = (row*4+c)%32

typedef __attribute__((ext_vector_type(8))) short bf16x8;
typedef __attribute__((ext_vector_type(4))) float f32x4;

// pack two floats into one dword of bf16 (round-half-up, 0.5-ulp like RNE)
__device__ inline unsigned pk2(float a, float b) {
    union { float f; unsigned u; } x, y; x.f = a; y.f = b;
    return ((x.u + 0x8000u) >> 16) | ((y.u + 0x8000u) & 0xFFFF0000u);
}

__global__ __launch_bounds__(256) void fused_mfma_kernel(
    const float* __restrict__ x,
    const int*   __restrict__ idx,
    const float* __restrict__ weight,
    const float* __restrict__ bias,
    float*       __restrict__ out)
{
    const int t    = threadIdx.x;
    const int lane = t & 63;
    const int wav  = t >> 6;
    const int quad = lane >> 4;
    const int li   = lane & 15;

    const int j    = blockIdx.z;
    const int cb0  = blockIdx.x * CB;
    const int lg0b = blockIdx.y * LB;
    const int b    = lg0b >> 10;          // 128-tiles never straddle b
    const int l0b  = lg0b & 1023;

    __shared__ unsigned Asl[32 * LDP];    // [k2_local][c]  (64 k per phase)
    __shared__ unsigned Bsl[32 * LDP];    // [k2_local][l]

    const int c_locb = (wav & 1) * 64;    // wave's c-half within block
    const int l_locb = (wav >> 1) * 64;   // wave's l-half

    const float* __restrict__ wbase = weight + j * (KD * C_DIM) + cb0;
    const float* __restrict__ xbase = x + (b << 18) + l0b;

    const int sc4  = (t & 31) * 4;        // staging column (c or l), float4
    const int srow = t >> 5;              // 0..7: pair-row within iter group

    f32x4 acc[4][4];
    #pragma unroll
    for (int mt = 0; mt < 4; ++mt)
        #pragma unroll
        for (int nt = 0; nt < 4; ++nt)
            acc[mt][nt] = (f32x4){0.f, 0.f, 0.f, 0.f};

    for (int p = 0; p < 4; ++p) {
        const int k0 = p * 64;

        // ---- stage 64 k's of A and B (row-pair float4 loads, packed) ----
        #pragma unroll
        for (int i = 0; i < 4; ++i) {
            const int kp = i * 8 + srow;             // local pair idx 0..31
            const int k  = k0 + kp * 2;
            const float4 a0 = *(const float4*)(wbase + k * C_DIM + sc4);
            const float4 a1 = *(const float4*)(wbase + (k + 1) * C_DIM + sc4);
            const float4 b0 = *(const float4*)(xbase + (k << 10) + sc4);
            const float4 b1 = *(const float4*)(xbase + ((k + 1) << 10) + sc4);
            uint4 pa, pb;
            pa.x = pk2(a0.x, a1.x); pa.y = pk2(a0.y, a1.y);
            pa.z = pk2(a0.z, a1.z); pa.w = pk2(a0.w, a1.w);
            pb.x = pk2(b0.x, b1.x); pb.y = pk2(b0.y, b1.y);
            pb.z = pk2(b0.z, b1.z); pb.w = pk2(b0.w, b1.w);
            *(uint4*)&Asl[kp * LDP + sc4] = pa;
            *(uint4*)&Bsl[kp * LDP + sc4] = pb;
        }
        __syncthreads();

        // ---- compute 2 chunks of K=32 from LDS ----
        #pragma unroll
        for (int h = 0; h < 2; ++h) {
            const int rbase = h * 16 + quad * 4;     // k2 row base for this quad
            bf16x8 af[4], bfr[4];
            #pragma unroll
            for (int mt = 0; mt < 4; ++mt) {
                const int cl = c_locb + mt * 16 + li;
                uint4 u;
                u.x = Asl[(rbase + 0) * LDP + cl];
                u.y = Asl[(rbase + 1) * LDP + cl];
                u.z = Asl[(rbase + 2) * LDP + cl];
                u.w = Asl[(rbase + 3) * LDP + cl];
                af[mt] = __builtin_bit_cast(bf16x8, u);
            }
            #pragma unroll
            for (int nt = 0; nt < 4; ++nt) {
                const int ll = l_locb + nt * 16 + li;
                uint4 u;
                u.x = Bsl[(rbase + 0) * LDP + ll];
                u.y = Bsl[(rbase + 1) * LDP + ll];
                u.z = Bsl[(rbase + 2) * LDP + ll];
                u.w = Bsl[(rbase + 3) * LDP + ll];
                bfr[nt] = __builtin_bit_cast(bf16x8, u);
            }
            #pragma unroll
            for (int mt = 0; mt < 4; ++mt)
                #pragma unroll
                for (int nt = 0; nt < 4; ++nt)
                    acc[mt][nt] = __builtin_amdgcn_mfma_f32_16x16x32_bf16(
                        af[mt], bfr[nt], acc[mt][nt], 0, 0, 0);
        }
        __syncthreads();
    }

    // ---- epilogue: masked scatter to out (b,c,l), idx/bias hoisted ----
    bool keep[4];
    int  lgv[4];
    #pragma unroll
    for (int nt = 0; nt < 4; ++nt) {
        lgv[nt]  = lg0b + l_locb + nt * 16 + li;
        keep[nt] = (idx[lgv[nt]] == j);
    }
    #pragma unroll
    for (int mt = 0; mt < 4; ++mt) {
        const int cb = cb0 + c_locb + mt * 16 + quad * 4;
        const float4 bb = *(const float4*)(bias + j * C_DIM + cb);
        #pragma unroll
        for (int nt = 0; nt < 4; ++nt) {
            if (!keep[nt]) continue;
            float* __restrict__ op = out + (b << 18) + (cb << 10) + (lgv[nt] & 1023);
            op[0 << 10] = acc[mt][nt][0] + bb.x;
            op[1 << 10] = acc[mt][nt][1] + bb.y;
            op[2 << 10] = acc[mt][nt][2] + bb.z;
            op[3 << 10] = acc[mt][nt][3] + bb.w;
        }
    }
}

extern "C" void kernel_launch(void* const* d_in, const int* in_sizes, int n_in,
                              void* d_out, int out_size, void* d_ws, size_t ws_size,
                              hipStream_t stream)
{
    const float* x      = (const float*)d_in[0];
    const int*   idx    = (const int*)  d_in[1];
    const float* weight = (const float*)d_in[2];
    const float* bias   = (const float*)d_in[3];
    float*       out    = (float*)      d_out;

    // grid: (2 c-tiles, 32 l-tiles, 8 j) = 512 blocks = 2 blocks/CU; j is
    // slowest so the 8 j-blocks of a (c,l) tile share an XCD residue ->
    // L2 merges their partial output lines.
    fused_mfma_kernel<<<dim3(2, 32, 8), 256, 0, stream>>>(x, idx, weight, bias, out);
}

// Round 12
// 72.368 us; speedup vs baseline: 1.1698x; 1.0236x over previous
//
#include <hip/hip_runtime.h>

// out[b,c,l] = sum_r x[b,r,l] * weight[idx[b,l], r, c] + bias[idx[b,l], c]
//   x:       (4, 256, 32, 32) fp32   flat (b*256 + r)*1024 + l
//   indexes: (4096,) int             j in [0,8)
//   weight:  (8, 256, 256) fp32     (j*256 + r)*256 + c
//   bias:    (8, 256) fp32
//   out:     (4, 256, 32, 32) fp32  (b*256 + c)*1024 + l
//
// R12: R11 (dense redundant-j MFMA, K-phased LDS staging, k-pair-packed
// dword LDS layout) + DOUBLE-BUFFERED phases: global loads for phase p+1
// are issued before compute of phase p and stay in flight across the
// barrier; one barrier per phase (5 total vs 8). This attacks the
// barrier-drain latency that kept the kernel ~3x above its bandwidth
// arithmetic (~17 us residual vs ~5 us model).
//
// Fragment layouts verified on HW in R8 (16x16x32 bf16):
//   A[m=lane&15][k=quad*8+i], B[k=quad*8+i][n=lane&15], D[m=quad*4+r][n=lane&15]

#define C_DIM 256
#define KD    256
#define CB    128      // c per block
#define LB    128      // l per block
#define LDP   132      // LDS row stride (dwords): (row*132+c)%32 = (row*4+c)%32

typedef __attribute__((ext_vector_type(8))) short bf16x8;
typedef __attribute__((ext_vector_type(4))) float f32x4;

// pack two floats into one dword of bf16 (round-half-up, 0.5-ulp like RNE)
__device__ inline unsigned pk2(float a, float b) {
    union { float f; unsigned u; } x, y; x.f = a; y.f = b;
    return ((x.u + 0x8000u) >> 16) | ((y.u + 0x8000u) & 0xFFFF0000u);
}

__global__ __launch_bounds__(256, 2) void fused_mfma_kernel(
    const float* __restrict__ x,
    const int*   __restrict__ idx,
    const float* __restrict__ weight,
    const float* __restrict__ bias,
    float*       __restrict__ out)
{
    const int t    = threadIdx.x;
    const int lane = t & 63;
    const int wav  = t >> 6;
    const int quad = lane >> 4;
    const int li   = lane & 15;

    const int j    = blockIdx.z;
    const int cb0  = blockIdx.x * CB;
    const int lg0b = blockIdx.y * LB;
    const int b    = lg0b >> 10;          // 128-tiles never straddle b
    const int l0b  = lg0b & 1023;

    __shared__ unsigned Asl[2][32 * LDP]; // [buf][k2_local][c]  (64 k/phase)
    __shared__ unsigned Bsl[2][32 * LDP]; // [buf][k2_local][l]

    const int c_locb = (wav & 1) * 64;    // wave's c-half within block
    const int l_locb = (wav >> 1) * 64;   // wave's l-half

    const float* __restrict__ wbase = weight + j * (KD * C_DIM) + cb0;
    const float* __restrict__ xbase = x + (b << 18) + l0b;

    const int sc4  = (t & 31) * 4;        // staging column (c or l), float4
    const int srow = t >> 5;              // 0..7: pair-row within iter group

    f32x4 acc[4][4];
    #pragma unroll
    for (int mt = 0; mt < 4; ++mt)
        #pragma unroll
        for (int nt = 0; nt < 4; ++nt)
            acc[mt][nt] = (f32x4){0.f, 0.f, 0.f, 0.f};

    // ---- prologue: load + stage phase 0 into buffer 0 ----
    float4 a0[4], a1[4], b0[4], b1[4];
    #pragma unroll
    for (int i = 0; i < 4; ++i) {
        const int kp = i * 8 + srow;
        const int k  = kp * 2;
        a0[i] = *(const float4*)(wbase + k * C_DIM + sc4);
        a1[i] = *(const float4*)(wbase + (k + 1) * C_DIM + sc4);
        b0[i] = *(const float4*)(xbase + (k << 10) + sc4);
        b1[i] = *(const float4*)(xbase + ((k + 1) << 10) + sc4);
    }
    #pragma unroll
    for (int i = 0; i < 4; ++i) {
        const int kp = i * 8 + srow;
        uint4 pa, pb;
        pa.x = pk2(a0[i].x, a1[i].x); pa.y = pk2(a0[i].y, a1[i].y);
        pa.z = pk2(a0[i].z, a1[i].z); pa.w = pk2(a0[i].w, a1[i].w);
        pb.x = pk2(b0[i].x, b1[i].x); pb.y = pk2(b0[i].y, b1[i].y);
        pb.z = pk2(b0[i].z, b1[i].z); pb.w = pk2(b0[i].w, b1[i].w);
        *(uint4*)&Asl[0][kp * LDP + sc4] = pa;
        *(uint4*)&Bsl[0][kp * LDP + sc4] = pb;
    }
    __syncthreads();

    #pragma unroll
    for (int p = 0; p < 4; ++p) {
        // 1. issue next phase's global loads (in flight across compute+barrier)
        if (p < 3) {
            const int k0 = (p + 1) * 64;
            #pragma unroll
            for (int i = 0; i < 4; ++i) {
                const int kp = i * 8 + srow;
                const int k  = k0 + kp * 2;
                a0[i] = *(const float4*)(wbase + k * C_DIM + sc4);
                a1[i] = *(const float4*)(wbase + (k + 1) * C_DIM + sc4);
                b0[i] = *(const float4*)(xbase + (k << 10) + sc4);
                b1[i] = *(const float4*)(xbase + ((k + 1) << 10) + sc4);
            }
        }

        // 2. compute 2 chunks of K=32 from buffer p&1
        const unsigned* __restrict__ Ab = Asl[p & 1];
        const unsigned* __restrict__ Bb = Bsl[p & 1];
        #pragma unroll
        for (int h = 0; h < 2; ++h) {
            const int rbase = h * 16 + quad * 4;
            bf16x8 af[4], bfr[4];
            #pragma unroll
            for (int mt = 0; mt < 4; ++mt) {
                const int cl = c_locb + mt * 16 + li;
                uint4 u;
                u.x = Ab[(rbase + 0) * LDP + cl];
                u.y = Ab[(rbase + 1) * LDP + cl];
                u.z = Ab[(rbase + 2) * LDP + cl];
                u.w = Ab[(rbase + 3) * LDP + cl];
                af[mt] = __builtin_bit_cast(bf16x8, u);
            }
            #pragma unroll
            for (int nt = 0; nt < 4; ++nt) {
                const int ll = l_locb + nt * 16 + li;
                uint4 u;
                u.x = Bb[(rbase + 0) * LDP + ll];
                u.y = Bb[(rbase + 1) * LDP + ll];
                u.z = Bb[(rbase + 2) * LDP + ll];
                u.w = Bb[(rbase + 3) * LDP + ll];
                bfr[nt] = __builtin_bit_cast(bf16x8, u);
            }
            #pragma unroll
            for (int mt = 0; mt < 4; ++mt)
                #pragma unroll
                for (int nt = 0; nt < 4; ++nt)
                    acc[mt][nt] = __builtin_amdgcn_mfma_f32_16x16x32_bf16(
                        af[mt], bfr[nt], acc[mt][nt], 0, 0, 0);
        }

        // 3. pack + write next phase into the alternate buffer, then barrier
        if (p < 3) {
            const int q = (p + 1) & 1;
            #pragma unroll
            for (int i = 0; i < 4; ++i) {
                const int kp = i * 8 + srow;
                uint4 pa, pb;
                pa.x = pk2(a0[i].x, a1[i].x); pa.y = pk2(a0[i].y, a1[i].y);
                pa.z = pk2(a0[i].z, a1[i].z); pa.w = pk2(a0[i].w, a1[i].w);
                pb.x = pk2(b0[i].x, b1[i].x); pb.y = pk2(b0[i].y, b1[i].y);
                pb.z = pk2(b0[i].z, b1[i].z); pb.w = pk2(b0[i].w, b1[i].w);
                *(uint4*)&Asl[q][kp * LDP + sc4] = pa;
                *(uint4*)&Bsl[q][kp * LDP + sc4] = pb;
            }
            __syncthreads();
        }
    }

    // ---- epilogue: masked scatter to out (b,c,l), idx/bias hoisted ----
    bool keep[4];
    int  lgv[4];
    #pragma unroll
    for (int nt = 0; nt < 4; ++nt) {
        lgv[nt]  = lg0b + l_locb + nt * 16 + li;
        keep[nt] = (idx[lgv[nt]] == j);
    }
    #pragma unroll
    for (int mt = 0; mt < 4; ++mt) {
        const int cb = cb0 + c_locb + mt * 16 + quad * 4;
        const float4 bb = *(const float4*)(bias + j * C_DIM + cb);
        #pragma unroll
        for (int nt = 0; nt < 4; ++nt) {
            if (!keep[nt]) continue;
            float* __restrict__ op = out + (b << 18) + (cb << 10) + (lgv[nt] & 1023);
            op[0 << 10] = acc[mt][nt][0] + bb.x;
            op[1 << 10] = acc[mt][nt][1] + bb.y;
            op[2 << 10] = acc[mt][nt][2] + bb.z;
            op[3 << 10] = acc[mt][nt][3] + bb.w;
        }
    }
}

extern "C" void kernel_launch(void* const* d_in, const int* in_sizes, int n_in,
                              void* d_out, int out_size, void* d_ws, size_t ws_size,
                              hipStream_t stream)
{
    const float* x      = (const float*)d_in[0];
    const int*   idx    = (const int*)  d_in[1];
    const float* weight = (const float*)d_in[2];
    const float* bias   = (const float*)d_in[3];
    float*       out    = (float*)      d_out;

    // grid: (2 c-tiles, 32 l-tiles, 8 j) = 512 blocks = 2 blocks/CU; j is
    // slowest so the 8 j-blocks of a (c,l) tile share an XCD residue ->
    // L2 merges their partial output lines.
    fused_mfma_kernel<<<dim3(2, 32, 8), 256, 0, stream>>>(x, idx, weight, bias, out);
}